// Round 4
// baseline (3865.432 us; speedup 1.0000x reference)
//
#include <hip/hip_runtime.h>

// PointNetSAModule on MI355X (gfx950).
// B=16, N=8192, CIN=64, S=1024, K=32, radius=0.2, MLP 67->64->64->128, eps=1e-5.
// DTYPES (proven R2/R3): inputs float32, outputs float32. Compare tolerance is
// bf16-policy (0.118) but storage is f32 per the reference's declared dtypes.
//
// ws footprint = 1,088,512 B exactly (R2 ran this size without faulting).
//
// Pipeline: prep -> fps -> ballq -> mlp_pass<0>,fin -> <1>,fin -> <2>,fin -> <3>
//   fps    : exact f32 FPS, 1 block/batch, coords in registers, winner coords
//            carried through the argmax reduction (1 barrier/step, dbuf slots)
//   ballq  : first-32-ascending-indices within radius (== top_k on score n-j)
//   mlp    : f16-pair dot2 MLP, 4 recompute passes for the 3 batchnorm stats,
//            final pass fuses BN+ReLU+maxpool over K
//   Exactness: FPS/ballq distances use __fsub_rn/__fmul_rn/__fadd_rn in numpy's
//   reduction order ((dx^2+dy^2)+dz^2) -- index decisions must be bit-exact.

typedef unsigned short u16;
typedef unsigned int   u32;

#define NB    16
#define NPTS  8192
#define CINF  64
#define NS    1024
#define KK    32
#define NSAMP (NB*NS*KK)   // 524288

typedef _Float16 h2v __attribute__((ext_vector_type(2)));

static __device__ __forceinline__ h2v asH2(u32 x){ union{u32 u; h2v h;} v; v.u=x; return v.h; }
static __device__ __forceinline__ u32 packh(float lo, float hi){
  union{ _Float16 h[2]; u32 u; } v;
  v.h[0]=(_Float16)lo; v.h[1]=(_Float16)hi; return v.u;
}
static __device__ __forceinline__ u32 f16bits(float z){
  union{ _Float16 h; u16 s; } v; v.h=(_Float16)z; return (u32)v.s;
}
static __device__ __forceinline__ float fdot2(h2v a, h2v b, float c){
#if __has_builtin(__builtin_amdgcn_fdot2)
  return __builtin_amdgcn_fdot2(a,b,c,false);   // v_dot2_f32_f16
#else
  return c + (float)a[0]*(float)b[0] + (float)a[1]*(float)b[1];
#endif
}

// exact-order d^2, matching numpy f32: (dx*dx + dy*dy) + dz*dz, no FMA contraction
static __device__ __forceinline__ float d2_exact(float ax,float ay,float az,float bx,float by,float bz){
  float dx=__fsub_rn(ax,bx), dy=__fsub_rn(ay,by), dz=__fsub_rn(az,bz);
  return __fadd_rn(__fadd_rn(__fmul_rn(dx,dx),__fmul_rn(dy,dy)),__fmul_rn(dz,dz));
}

// ---------------------------------------------------------------- prep ----
__global__ void prep_kernel(const float* __restrict__ W0, const float* __restrict__ W1,
                            const float* __restrict__ W2,
                            u32* __restrict__ Wp0, u32* __restrict__ Wp1, u32* __restrict__ Wp2,
                            float* __restrict__ stats)
{
  const int t = threadIdx.x;
  for (int i=t;i<768;i+=256) stats[i]=0.f;
  // W0: (64,67) -> rows of 36 uints (34 f16x2 pairs + 2 pad)
  for (int i=t;i<64*36;i+=256){
    int c = i/36, u = i - c*36;
    int j0 = 2*u, j1 = 2*u+1;
    float lo = (j0<67)? W0[c*67+j0] : 0.f;
    float hi = (j1<67)? W0[c*67+j1] : 0.f;
    Wp0[i] = packh(lo,hi);
  }
  for (int i=t;i<64*32;i+=256){            // W1 (64,64) -> 32 pairs/row
    int c = i>>5, u = i&31;
    Wp1[i] = packh(W1[c*64+2*u], W1[c*64+2*u+1]);
  }
  for (int i=t;i<128*32;i+=256){           // W2 (128,64)
    int c = i>>5, u = i&31;
    Wp2[i] = packh(W2[c*64+2*u], W2[c*64+2*u+1]);
  }
}

// ----------------------------------------------------------------- FPS ----
// one block per batch; 32 f32 points/thread in registers; winner coords carried
// through the reduction (no coord mirror, one barrier per step via dbuf slots).
__global__ __launch_bounds__(256,1) void fps_kernel(const float* __restrict__ xyz,
    float* __restrict__ out_xyz)
{
  const int b = blockIdx.x, t = threadIdx.x;
  const float* xb = xyz + (size_t)b*3*NPTS;
  __shared__ float s_v[2][4], s_x[2][4], s_y[2][4], s_z[2][4];
  __shared__ int   s_i[2][4];
  float px[32],py[32],pz[32],dist[32];
  #pragma unroll
  for (int i=0;i<32;i++){
    const int idx = t + 256*i;
    px[i]=xb[idx]; py[i]=xb[NPTS+idx]; pz[i]=xb[2*NPTS+idx];
    dist[i]=__builtin_inff();
  }
  float cx = xb[0], cy = xb[NPTS], cz = xb[2*NPTS];   // initial center = point 0
  const int lane = t & 63, wv = t >> 6;
  for (int step=0; step<NS; step++){
    if (t==0){
      out_xyz[(size_t)(b*3+0)*NS+step]=cx;
      out_xyz[(size_t)(b*3+1)*NS+step]=cy;
      out_xyz[(size_t)(b*3+2)*NS+step]=cz;
    }
    if (step==NS-1) break;
    float bv=-1.f; int bi=0; float bx=cx, by=cy, bz=cz;
    #pragma unroll
    for (int i=0;i<32;i++){
      float d2 = d2_exact(px[i],py[i],pz[i], cx,cy,cz);
      float nd = fminf(dist[i], d2);
      dist[i]=nd;
      bool gt = nd>bv;                   // strict >: first-max (idx ascending in i)
      bv = gt?nd:bv; bi = gt?(t+256*i):bi;
      bx = gt?px[i]:bx; by = gt?py[i]:by; bz = gt?pz[i]:bz;
    }
    #pragma unroll
    for (int off=1; off<64; off<<=1){    // wave argmax, smallest-index tie-break
      float ov=__shfl_xor(bv,off); int oi=__shfl_xor(bi,off);
      float ox=__shfl_xor(bx,off), oy=__shfl_xor(by,off), oz=__shfl_xor(bz,off);
      bool take = (ov>bv) || (ov==bv && oi<bi);
      bv=take?ov:bv; bi=take?oi:bi; bx=take?ox:bx; by=take?oy:by; bz=take?oz:bz;
    }
    const int p = step&1;                // double-buffered -> single barrier/step
    if (lane==0){ s_v[p][wv]=bv; s_i[p][wv]=bi; s_x[p][wv]=bx; s_y[p][wv]=by; s_z[p][wv]=bz; }
    __syncthreads();
    bv=s_v[p][0]; bi=s_i[p][0]; bx=s_x[p][0]; by=s_y[p][0]; bz=s_z[p][0];
    #pragma unroll
    for (int w=1;w<4;w++){
      float ov=s_v[p][w]; int oi=s_i[p][w];
      bool take = (ov>bv) || (ov==bv && oi<bi);
      bv=take?ov:bv; bi=take?oi:bi;
      bx=take?s_x[p][w]:bx; by=take?s_y[p][w]:by; bz=take?s_z[p][w]:bz;
    }
    cx=bx; cy=by; cz=bz;
  }
}

// ---------------------------------------------------------- ball query ----
// one wave per center; first 32 ascending indices with d2 < 0.04; pad with first.
// f32 centers read from out_xyz (exact values fps selected).
__global__ __launch_bounds__(256) void ballq_kernel(const float* __restrict__ xyz,
    const float* __restrict__ out_xyz, u16* __restrict__ gidx)
{
  const int gid = blockIdx.x*4 + (threadIdx.x>>6);
  const int lane = threadIdx.x & 63;
  const int b = gid >> 10, s = gid & (NS-1);
  const float* xb = xyz + (size_t)b*3*NPTS;
  const float cx = out_xyz[(size_t)(b*3+0)*NS+s];
  const float cy = out_xyz[(size_t)(b*3+1)*NS+s];
  const float cz = out_xyz[(size_t)(b*3+2)*NS+s];
  u16* out = gidx + (size_t)gid*KK;
  int cnt=0, first=-1;
  for (int base=0; base<NPTS; base+=64){
    const int pidx = base + lane;
    float d2 = d2_exact(cx,cy,cz, xb[pidx], xb[NPTS+pidx], xb[2*NPTS+pidx]);
    bool within = d2 < 0.04f;
    unsigned long long m = __ballot(within);
    if (m){
      if (first<0) first = base + (__ffsll(m)-1);
      int pos = cnt + (int)__popcll(m & ((1ull<<lane)-1ull));
      if (within && pos<KK) out[pos]=(u16)pidx;
      cnt += (int)__popcll(m);
      if (cnt>=KK) break;
    }
  }
  if (first<0) first=0;                  // unreachable (center self-hit)
  for (int posi = cnt + lane; posi < KK; posi += 64) out[posi]=(u16)first;
}

// --------------------------------------------------------------- MLP -----
// wrow is wave-uniform -> s_load; dot2 with SGPR weight operand. 2 acc chains.
template<int PAIRS>
static __device__ __forceinline__ float dotrow(const u32* __restrict__ wrow, const u32* x){
  float a=0.f, b=0.f;
  #pragma unroll
  for (int u=0;u<PAIRS;u+=2){
    a = fdot2(asH2(x[u]),   asH2(wrow[u]),   a);
    if (u+1<PAIRS) b = fdot2(asH2(x[u+1]), asH2(wrow[u+1]), b);
  }
  return __fadd_rn(a,b);
}

// STAGE 0: stats of y1 | 1: stats of y2 | 2: stats of y3 | 3: final + maxpool
template<int STAGE>
__global__ __launch_bounds__(256,2) void mlp_pass(
    const float* __restrict__ xyz, const float* __restrict__ feat,
    const float* __restrict__ out_xyz, const u16* __restrict__ gidx,
    const u32* __restrict__ Wp0, const u32* __restrict__ Wp1, const u32* __restrict__ Wp2,
    const float* __restrict__ affine, float* __restrict__ stats, float* __restrict__ outF)
{
  constexpr int TCO = (STAGE==2)?128:64;       // stats channel count
  constexpr int RB  = (TCO==128)?16:32;        // LDS stat bins stripe
  __shared__ u32   hbuf[(STAGE>=1)? 256*34 : 4];   // per-thread h staging (stride 34 dwords)
  __shared__ float bins[(STAGE<=2)? TCO*2*RB : 4];

  const int t = threadIdx.x;
  if constexpr (STAGE<=2){
    for (int i=t;i<TCO*2*RB;i+=256) bins[i]=0.f;
    __syncthreads();
  }
  const int ss = blockIdx.x*256 + t;           // flat (b,s,k)
  const int b = ss >> 15;
  const int s = (ss >> 5) & (NS-1);
  const int g = ((int)gidx[ss]) & (NPTS-1);    // clamp: never OOB
  const float* xb = xyz + (size_t)b*3*NPTS;
  const float* fb = feat + (size_t)b*CINF*NPTS;
  const float cx = out_xyz[(size_t)(b*3+0)*NS+s];
  const float cy = out_xyz[(size_t)(b*3+1)*NS+s];
  const float cz = out_xyz[(size_t)(b*3+2)*NS+s];

  // gather x = [xyz[g]-center ; feat[:,g]] as 34 packed f16 pairs (j=67 padded 0)
  u32 xh[34];
  {
    float dx = __fsub_rn(xb[g],        cx);
    float dy = __fsub_rn(xb[NPTS+g],   cy);
    float dz = __fsub_rn(xb[2*NPTS+g], cz);
    xh[0] = packh(dx,dy);
    xh[1] = packh(dz, fb[g]);                          // f[0]
    #pragma unroll
    for (int u=2;u<33;u++)                             // f[2u-3], f[2u-2]
      xh[u] = packh(fb[(size_t)(2*u-3)*NPTS+g], fb[(size_t)(2*u-2)*NPTS+g]);
    xh[33] = packh(fb[(size_t)63*NPTS+g], 0.f);        // f[63], pad
  }

  const int r = t & (RB-1);
  u32 pend=0;

  // ---- layer 1 (67->64) ----
  #pragma unroll 1
  for (int c=0;c<64;c++){
    float y = dotrow<34>(Wp0 + c*36, xh);
    if constexpr (STAGE==0){
      atomicAdd(&bins[c*RB+r], y);
      atomicAdd(&bins[TCO*RB + c*RB+r], __fmul_rn(y,y));
    } else {
      float z = fmaxf(fmaf(y, affine[2*c], affine[2*c+1]), 0.f);
      u32 hb = f16bits(z);
      if ((c&1)==0) pend = hb; else hbuf[t*34 + (c>>1)] = pend | (hb<<16);
    }
  }

  if constexpr (STAGE>=1){
    alignas(16) u32 ha[32];
    #pragma unroll
    for (int u=0;u<16;u++) *(uint2*)&ha[2*u] = *(const uint2*)&hbuf[t*34 + 2*u];
    // ---- layer 2 (64->64) ----
    #pragma unroll 1
    for (int c=0;c<64;c++){
      float y = dotrow<32>(Wp1 + c*32, ha);
      if constexpr (STAGE==1){
        atomicAdd(&bins[c*RB+r], y);
        atomicAdd(&bins[TCO*RB + c*RB+r], __fmul_rn(y,y));
      } else {
        float z = fmaxf(fmaf(y, affine[256+2*c], affine[256+2*c+1]), 0.f);
        u32 hb = f16bits(z);
        if ((c&1)==0) pend = hb; else hbuf[t*34 + (c>>1)] = pend | (hb<<16);
      }
    }
    if constexpr (STAGE>=2){
      #pragma unroll
      for (int u=0;u<16;u++) *(uint2*)&ha[2*u] = *(const uint2*)&hbuf[t*34 + 2*u];
      // ---- layer 3 (64->128) ----
      #pragma unroll 1
      for (int c=0;c<128;c++){
        float y = dotrow<32>(Wp2 + c*32, ha);
        if constexpr (STAGE==2){
          atomicAdd(&bins[c*RB+r], y);
          atomicAdd(&bins[TCO*RB + c*RB+r], __fmul_rn(y,y));
        } else {
          float z = fmaxf(fmaf(y, affine[512+2*c], affine[512+2*c+1]), 0.f);
          #pragma unroll
          for (int off=1; off<32; off<<=1) z = fmaxf(z, __shfl_xor(z, off)); // max over K
          if ((t&31)==0) outF[((size_t)b*128 + c)*NS + s] = z;
        }
      }
    }
  }

  if constexpr (STAGE<=2){
    __syncthreads();
    if (t < TCO){
      float s1=0.f, s2=0.f;
      #pragma unroll
      for (int q=0;q<RB;q++){ s1 += bins[t*RB+q]; s2 += bins[TCO*RB+t*RB+q]; }
      atomicAdd(&stats[STAGE*256 + 2*t],   s1);
      atomicAdd(&stats[STAGE*256 + 2*t+1], s2);
    }
  }
}

// ----------------------------------------------------------- finalize ----
__global__ void finalize_kernel(const float* __restrict__ st, float* __restrict__ af,
                                const float* __restrict__ gamma, const float* __restrict__ beta, int C)
{
  int c = threadIdx.x;
  if (c < C){
    float mean = st[2*c] * (1.f/524288.f);
    float var  = fmaxf(st[2*c+1] * (1.f/524288.f) - mean*mean, 0.f);
    float rstd = 1.f / sqrtf(var + 1e-5f);
    float sc = rstd * gamma[c];
    af[2*c]   = sc;
    af[2*c+1] = beta[c] - mean*sc;
  }
}

// ------------------------------------------------------------- launch ----
extern "C" void kernel_launch(void* const* d_in, const int* in_sizes, int n_in,
                              void* d_out, int out_size, void* d_ws, size_t ws_size,
                              hipStream_t stream)
{
  (void)in_sizes; (void)n_in; (void)out_size; (void)ws_size;
  const float* xyz  = (const float*)d_in[0];
  const float* feat = (const float*)d_in[1];
  const float* W0 = (const float*)d_in[2];
  const float* g0 = (const float*)d_in[3];
  const float* b0 = (const float*)d_in[4];
  const float* W1 = (const float*)d_in[5];
  const float* g1 = (const float*)d_in[6];
  const float* b1 = (const float*)d_in[7];
  const float* W2 = (const float*)d_in[8];
  const float* g2 = (const float*)d_in[9];
  const float* b2 = (const float*)d_in[10];

  char* ws = (char*)d_ws;                      // 1,088,512 B total (== R2's proven size)
  u16*   gidx    = (u16*)  (ws + 0);           // 524288 u16  = 1048576 B
  u32*   Wp0     = (u32*)  (ws + 1048576);     // 64*36 u32   =    9216 B
  u32*   Wp1     = (u32*)  (ws + 1057792);     // 64*32 u32   =    8192 B
  u32*   Wp2     = (u32*)  (ws + 1065984);     // 128*32 u32  =   16384 B
  float* stats   = (float*)(ws + 1082368);     // 3*128*2 f32 =    3072 B
  float* affine  = (float*)(ws + 1085440);     // 3*128*2 f32 =    3072 B

  float* out_xyz  = (float*)d_out;                         // (16,3,1024) f32
  float* out_feat = (float*)d_out + (size_t)NB*3*NS;       // (16,128,1024) f32

  prep_kernel<<<1,256,0,stream>>>(W0,W1,W2,Wp0,Wp1,Wp2,stats);
  fps_kernel<<<NB,256,0,stream>>>(xyz, out_xyz);
  ballq_kernel<<<NB*NS/4,256,0,stream>>>(xyz, out_xyz, gidx);

  mlp_pass<0><<<NSAMP/256,256,0,stream>>>(xyz,feat,out_xyz,gidx,Wp0,Wp1,Wp2,affine,stats,out_feat);
  finalize_kernel<<<1,128,0,stream>>>(stats,     affine,     g0,b0, 64);
  mlp_pass<1><<<NSAMP/256,256,0,stream>>>(xyz,feat,out_xyz,gidx,Wp0,Wp1,Wp2,affine,stats,out_feat);
  finalize_kernel<<<1,128,0,stream>>>(stats+256, affine+256, g1,b1, 64);
  mlp_pass<2><<<NSAMP/256,256,0,stream>>>(xyz,feat,out_xyz,gidx,Wp0,Wp1,Wp2,affine,stats,out_feat);
  finalize_kernel<<<1,128,0,stream>>>(stats+512, affine+512, g2,b2, 128);
  mlp_pass<3><<<NSAMP/256,256,0,stream>>>(xyz,feat,out_xyz,gidx,Wp0,Wp1,Wp2,affine,stats,out_feat);
}

// Round 5
// 3461.353 us; speedup vs baseline: 1.1167x; 1.1167x over previous
//
#include <hip/hip_runtime.h>

// PointNetSAModule on MI355X (gfx950).
// B=16, N=8192, CIN=64, S=1024, K=32, radius=0.2, MLP 67->64->64->128, eps=1e-5.
// Inputs/outputs float32 (proven R4). ws footprint = 1,088,512 B (proven safe R2/R4).
//
// R4 -> R5: fps reworked for latency hiding (1024 thr, 8 pts/thread, slim argmax,
// winner coords via uniform broadcast load); mlp occupancy 2->4 blocks/CU + unroll 2.

typedef unsigned short u16;
typedef unsigned int   u32;

#define NB    16
#define NPTS  8192
#define CINF  64
#define NS    1024
#define KK    32
#define NSAMP (NB*NS*KK)   // 524288

typedef _Float16 h2v __attribute__((ext_vector_type(2)));

static __device__ __forceinline__ h2v asH2(u32 x){ union{u32 u; h2v h;} v; v.u=x; return v.h; }
static __device__ __forceinline__ u32 packh(float lo, float hi){
  union{ _Float16 h[2]; u32 u; } v;
  v.h[0]=(_Float16)lo; v.h[1]=(_Float16)hi; return v.u;
}
static __device__ __forceinline__ u32 f16bits(float z){
  union{ _Float16 h; u16 s; } v; v.h=(_Float16)z; return (u32)v.s;
}
static __device__ __forceinline__ float fdot2(h2v a, h2v b, float c){
#if __has_builtin(__builtin_amdgcn_fdot2)
  return __builtin_amdgcn_fdot2(a,b,c,false);   // v_dot2_f32_f16
#else
  return c + (float)a[0]*(float)b[0] + (float)a[1]*(float)b[1];
#endif
}

// exact-order d^2, matching numpy f32: (dx*dx + dy*dy) + dz*dz, no FMA contraction
static __device__ __forceinline__ float d2_exact(float ax,float ay,float az,float bx,float by,float bz){
  float dx=__fsub_rn(ax,bx), dy=__fsub_rn(ay,by), dz=__fsub_rn(az,bz);
  return __fadd_rn(__fadd_rn(__fmul_rn(dx,dx),__fmul_rn(dy,dy)),__fmul_rn(dz,dz));
}

// ---------------------------------------------------------------- prep ----
__global__ void prep_kernel(const float* __restrict__ W0, const float* __restrict__ W1,
                            const float* __restrict__ W2,
                            u32* __restrict__ Wp0, u32* __restrict__ Wp1, u32* __restrict__ Wp2,
                            float* __restrict__ stats)
{
  const int t = threadIdx.x;
  for (int i=t;i<768;i+=256) stats[i]=0.f;
  // W0: (64,67) -> rows of 36 uints (34 f16x2 pairs + 2 pad)
  for (int i=t;i<64*36;i+=256){
    int c = i/36, u = i - c*36;
    int j0 = 2*u, j1 = 2*u+1;
    float lo = (j0<67)? W0[c*67+j0] : 0.f;
    float hi = (j1<67)? W0[c*67+j1] : 0.f;
    Wp0[i] = packh(lo,hi);
  }
  for (int i=t;i<64*32;i+=256){            // W1 (64,64) -> 32 pairs/row
    int c = i>>5, u = i&31;
    Wp1[i] = packh(W1[c*64+2*u], W1[c*64+2*u+1]);
  }
  for (int i=t;i<128*32;i+=256){           // W2 (128,64)
    int c = i>>5, u = i&31;
    Wp2[i] = packh(W2[c*64+2*u], W2[c*64+2*u+1]);
  }
}

// ----------------------------------------------------------------- FPS ----
// one block per batch; 1024 threads, 8 f32 points/thread in registers.
// Argmax carries (bv,bi) only; winner coords re-fetched by all lanes via a
// same-address (broadcast) load — off the per-point select chain.
__global__ __launch_bounds__(1024,1) void fps_kernel(const float* __restrict__ xyz,
    float* __restrict__ out_xyz)
{
  const int b = blockIdx.x, t = threadIdx.x;
  const float* xb = xyz + (size_t)b*3*NPTS;
  __shared__ float s_v[2][16];
  __shared__ int   s_i[2][16];
  float px[8],py[8],pz[8],dist[8];
  #pragma unroll
  for (int i=0;i<8;i++){
    const int idx = t + 1024*i;
    px[i]=xb[idx]; py[i]=xb[NPTS+idx]; pz[i]=xb[2*NPTS+idx];
    dist[i]=__builtin_inff();
  }
  float cx = xb[0], cy = xb[NPTS], cz = xb[2*NPTS];   // initial center = point 0
  const int lane = t & 63, wv = t >> 6, l16 = lane & 15;
  for (int step=0; step<NS; step++){
    if (t==0){
      out_xyz[(size_t)(b*3+0)*NS+step]=cx;
      out_xyz[(size_t)(b*3+1)*NS+step]=cy;
      out_xyz[(size_t)(b*3+2)*NS+step]=cz;
    }
    if (step==NS-1) break;
    float bv=-1.f; int bi=0;
    #pragma unroll
    for (int i=0;i<8;i++){
      float d2 = d2_exact(px[i],py[i],pz[i], cx,cy,cz);
      float nd = fminf(dist[i], d2);
      dist[i]=nd;
      bool gt = nd>bv;                   // strict >: keeps smallest idx (i ascending)
      bv = gt?nd:bv; bi = gt?(t+1024*i):bi;
    }
    #pragma unroll
    for (int off=1; off<64; off<<=1){    // wave argmax, smallest-index tie-break
      float ov=__shfl_xor(bv,off); int oi=__shfl_xor(bi,off);
      bool take = (ov>bv) || (ov==bv && oi<bi);
      bv=take?ov:bv; bi=take?oi:bi;
    }
    const int p = step&1;                // double-buffered -> single barrier/step
    if (lane==0){ s_v[p][wv]=bv; s_i[p][wv]=bi; }
    __syncthreads();
    bv = s_v[p][l16]; bi = s_i[p][l16];  // 16 wave slots -> lanes, 4-level reduce
    #pragma unroll
    for (int off=1; off<16; off<<=1){
      float ov=__shfl_xor(bv,off); int oi=__shfl_xor(bi,off);
      bool take = (ov>bv) || (ov==bv && oi<bi);
      bv=take?ov:bv; bi=take?oi:bi;
    }
    // bi now identical on all lanes/waves -> broadcast load of winner coords
    cx = xb[bi]; cy = xb[NPTS+bi]; cz = xb[2*NPTS+bi];
  }
}

// ---------------------------------------------------------- ball query ----
// one wave per center; first 32 ascending indices with d2 < 0.04; pad with first.
__global__ __launch_bounds__(256) void ballq_kernel(const float* __restrict__ xyz,
    const float* __restrict__ out_xyz, u16* __restrict__ gidx)
{
  const int gid = blockIdx.x*4 + (threadIdx.x>>6);
  const int lane = threadIdx.x & 63;
  const int b = gid >> 10, s = gid & (NS-1);
  const float* xb = xyz + (size_t)b*3*NPTS;
  const float cx = out_xyz[(size_t)(b*3+0)*NS+s];
  const float cy = out_xyz[(size_t)(b*3+1)*NS+s];
  const float cz = out_xyz[(size_t)(b*3+2)*NS+s];
  u16* out = gidx + (size_t)gid*KK;
  int cnt=0, first=-1;
  for (int base=0; base<NPTS; base+=64){
    const int pidx = base + lane;
    float d2 = d2_exact(cx,cy,cz, xb[pidx], xb[NPTS+pidx], xb[2*NPTS+pidx]);
    bool within = d2 < 0.04f;
    unsigned long long m = __ballot(within);
    if (m){
      if (first<0) first = base + (__ffsll(m)-1);
      int pos = cnt + (int)__popcll(m & ((1ull<<lane)-1ull));
      if (within && pos<KK) out[pos]=(u16)pidx;
      cnt += (int)__popcll(m);
      if (cnt>=KK) break;
    }
  }
  if (first<0) first=0;                  // unreachable (center self-hit)
  for (int posi = cnt + lane; posi < KK; posi += 64) out[posi]=(u16)first;
}

// --------------------------------------------------------------- MLP -----
// wrow is wave-uniform -> s_load; dot2 with SGPR weight operand. 2 acc chains.
template<int PAIRS>
static __device__ __forceinline__ float dotrow(const u32* __restrict__ wrow, const u32* x){
  float a=0.f, b=0.f;
  #pragma unroll
  for (int u=0;u<PAIRS;u+=2){
    a = fdot2(asH2(x[u]),   asH2(wrow[u]),   a);
    if (u+1<PAIRS) b = fdot2(asH2(x[u+1]), asH2(wrow[u+1]), b);
  }
  return __fadd_rn(a,b);
}

// STAGE 0: stats of y1 | 1: stats of y2 | 2: stats of y3 | 3: final + maxpool
template<int STAGE>
__global__ __launch_bounds__(256,4) void mlp_pass(
    const float* __restrict__ xyz, const float* __restrict__ feat,
    const float* __restrict__ out_xyz, const u16* __restrict__ gidx,
    const u32* __restrict__ Wp0, const u32* __restrict__ Wp1, const u32* __restrict__ Wp2,
    const float* __restrict__ affine, float* __restrict__ stats, float* __restrict__ outF)
{
  constexpr int TCO = (STAGE==2)?128:64;       // stats channel count
  constexpr int RB  = (TCO==128)?16:32;        // LDS stat bins stripe
  __shared__ u32   hbuf[(STAGE>=1)? 256*34 : 4];   // per-thread h staging (stride 34 dwords)
  __shared__ float bins[(STAGE<=2)? TCO*2*RB : 4];

  const int t = threadIdx.x;
  if constexpr (STAGE<=2){
    for (int i=t;i<TCO*2*RB;i+=256) bins[i]=0.f;
    __syncthreads();
  }
  const int ss = blockIdx.x*256 + t;           // flat (b,s,k)
  const int b = ss >> 15;
  const int s = (ss >> 5) & (NS-1);
  const int g = ((int)gidx[ss]) & (NPTS-1);    // clamp: never OOB
  const float* xb = xyz + (size_t)b*3*NPTS;
  const float* fb = feat + (size_t)b*CINF*NPTS;
  const float cx = out_xyz[(size_t)(b*3+0)*NS+s];
  const float cy = out_xyz[(size_t)(b*3+1)*NS+s];
  const float cz = out_xyz[(size_t)(b*3+2)*NS+s];

  // gather x = [xyz[g]-center ; feat[:,g]] as 34 packed f16 pairs (j=67 padded 0)
  u32 xh[34];
  {
    float dx = __fsub_rn(xb[g],        cx);
    float dy = __fsub_rn(xb[NPTS+g],   cy);
    float dz = __fsub_rn(xb[2*NPTS+g], cz);
    xh[0] = packh(dx,dy);
    xh[1] = packh(dz, fb[g]);                          // f[0]
    #pragma unroll
    for (int u=2;u<33;u++)                             // f[2u-3], f[2u-2]
      xh[u] = packh(fb[(size_t)(2*u-3)*NPTS+g], fb[(size_t)(2*u-2)*NPTS+g]);
    xh[33] = packh(fb[(size_t)63*NPTS+g], 0.f);        // f[63], pad
  }

  const int r = t & (RB-1);
  u32 pend=0;

  // ---- layer 1 (67->64) ----
  #pragma unroll 2
  for (int c=0;c<64;c++){
    float y = dotrow<34>(Wp0 + c*36, xh);
    if constexpr (STAGE==0){
      atomicAdd(&bins[c*RB+r], y);
      atomicAdd(&bins[TCO*RB + c*RB+r], __fmul_rn(y,y));
    } else {
      float z = fmaxf(fmaf(y, affine[2*c], affine[2*c+1]), 0.f);
      u32 hb = f16bits(z);
      if ((c&1)==0) pend = hb; else hbuf[t*34 + (c>>1)] = pend | (hb<<16);
    }
  }

  if constexpr (STAGE>=1){
    alignas(16) u32 ha[32];
    #pragma unroll
    for (int u=0;u<16;u++) *(uint2*)&ha[2*u] = *(const uint2*)&hbuf[t*34 + 2*u];
    // ---- layer 2 (64->64) ----
    #pragma unroll 2
    for (int c=0;c<64;c++){
      float y = dotrow<32>(Wp1 + c*32, ha);
      if constexpr (STAGE==1){
        atomicAdd(&bins[c*RB+r], y);
        atomicAdd(&bins[TCO*RB + c*RB+r], __fmul_rn(y,y));
      } else {
        float z = fmaxf(fmaf(y, affine[256+2*c], affine[256+2*c+1]), 0.f);
        u32 hb = f16bits(z);
        if ((c&1)==0) pend = hb; else hbuf[t*34 + (c>>1)] = pend | (hb<<16);
      }
    }
    if constexpr (STAGE>=2){
      #pragma unroll
      for (int u=0;u<16;u++) *(uint2*)&ha[2*u] = *(const uint2*)&hbuf[t*34 + 2*u];
      // ---- layer 3 (64->128) ----
      #pragma unroll 2
      for (int c=0;c<128;c++){
        float y = dotrow<32>(Wp2 + c*32, ha);
        if constexpr (STAGE==2){
          atomicAdd(&bins[c*RB+r], y);
          atomicAdd(&bins[TCO*RB + c*RB+r], __fmul_rn(y,y));
        } else {
          float z = fmaxf(fmaf(y, affine[512+2*c], affine[512+2*c+1]), 0.f);
          #pragma unroll
          for (int off=1; off<32; off<<=1) z = fmaxf(z, __shfl_xor(z, off)); // max over K
          if ((t&31)==0) outF[((size_t)b*128 + c)*NS + s] = z;
        }
      }
    }
  }

  if constexpr (STAGE<=2){
    __syncthreads();
    if (t < TCO){
      float s1=0.f, s2=0.f;
      #pragma unroll
      for (int q=0;q<RB;q++){ s1 += bins[t*RB+q]; s2 += bins[TCO*RB+t*RB+q]; }
      atomicAdd(&stats[STAGE*256 + 2*t],   s1);
      atomicAdd(&stats[STAGE*256 + 2*t+1], s2);
    }
  }
}

// ----------------------------------------------------------- finalize ----
__global__ void finalize_kernel(const float* __restrict__ st, float* __restrict__ af,
                                const float* __restrict__ gamma, const float* __restrict__ beta, int C)
{
  int c = threadIdx.x;
  if (c < C){
    float mean = st[2*c] * (1.f/524288.f);
    float var  = fmaxf(st[2*c+1] * (1.f/524288.f) - mean*mean, 0.f);
    float rstd = 1.f / sqrtf(var + 1e-5f);
    float sc = rstd * gamma[c];
    af[2*c]   = sc;
    af[2*c+1] = beta[c] - mean*sc;
  }
}

// ------------------------------------------------------------- launch ----
extern "C" void kernel_launch(void* const* d_in, const int* in_sizes, int n_in,
                              void* d_out, int out_size, void* d_ws, size_t ws_size,
                              hipStream_t stream)
{
  (void)in_sizes; (void)n_in; (void)out_size; (void)ws_size;
  const float* xyz  = (const float*)d_in[0];
  const float* feat = (const float*)d_in[1];
  const float* W0 = (const float*)d_in[2];
  const float* g0 = (const float*)d_in[3];
  const float* b0 = (const float*)d_in[4];
  const float* W1 = (const float*)d_in[5];
  const float* g1 = (const float*)d_in[6];
  const float* b1 = (const float*)d_in[7];
  const float* W2 = (const float*)d_in[8];
  const float* g2 = (const float*)d_in[9];
  const float* b2 = (const float*)d_in[10];

  char* ws = (char*)d_ws;                      // 1,088,512 B total (proven safe)
  u16*   gidx    = (u16*)  (ws + 0);           // 524288 u16  = 1048576 B
  u32*   Wp0     = (u32*)  (ws + 1048576);     // 64*36 u32   =    9216 B
  u32*   Wp1     = (u32*)  (ws + 1057792);     // 64*32 u32   =    8192 B
  u32*   Wp2     = (u32*)  (ws + 1065984);     // 128*32 u32  =   16384 B
  float* stats   = (float*)(ws + 1082368);     // 3*128*2 f32 =    3072 B
  float* affine  = (float*)(ws + 1085440);     // 3*128*2 f32 =    3072 B

  float* out_xyz  = (float*)d_out;                         // (16,3,1024) f32
  float* out_feat = (float*)d_out + (size_t)NB*3*NS;       // (16,128,1024) f32

  prep_kernel<<<1,256,0,stream>>>(W0,W1,W2,Wp0,Wp1,Wp2,stats);
  fps_kernel<<<NB,1024,0,stream>>>(xyz, out_xyz);
  ballq_kernel<<<NB*NS/4,256,0,stream>>>(xyz, out_xyz, gidx);

  mlp_pass<0><<<NSAMP/256,256,0,stream>>>(xyz,feat,out_xyz,gidx,Wp0,Wp1,Wp2,affine,stats,out_feat);
  finalize_kernel<<<1,128,0,stream>>>(stats,     affine,     g0,b0, 64);
  mlp_pass<1><<<NSAMP/256,256,0,stream>>>(xyz,feat,out_xyz,gidx,Wp0,Wp1,Wp2,affine,stats,out_feat);
  finalize_kernel<<<1,128,0,stream>>>(stats+256, affine+256, g1,b1, 64);
  mlp_pass<2><<<NSAMP/256,256,0,stream>>>(xyz,feat,out_xyz,gidx,Wp0,Wp1,Wp2,affine,stats,out_feat);
  finalize_kernel<<<1,128,0,stream>>>(stats+512, affine+512, g2,b2, 128);
  mlp_pass<3><<<NSAMP/256,256,0,stream>>>(xyz,feat,out_xyz,gidx,Wp0,Wp1,Wp2,affine,stats,out_feat);
}

// Round 6
// 3255.747 us; speedup vs baseline: 1.1873x; 1.0632x over previous
//
#include <hip/hip_runtime.h>

// PointNetSAModule on MI355X (gfx950).
// B=16, N=8192, CIN=64, S=1024, K=32, radius=0.2, MLP 67->64->64->128, eps=1e-5.
// Inputs/outputs float32 (proven R4). ws footprint = 1,088,512 B (proven safe).
//
// R5 -> R6:
//  * fps: scalarized per-thread point state (R5 counters: VGPR_Count=32 proves the
//    compiler demoted the arrays and re-loaded coords from cache every step ->
//    ~2x issue cost). launch_bounds(1024,2) lifts the VGPR cap.
//  * mlp: pass3 (full 3-layer recompute + maxpool) eliminated. BN affine+relu is
//    monotone in y for scale>0 / anti-monotone for scale<0, so maxpool commutes:
//    pass2 stores (max_k y3, min_k y3) packed f16 in the out_feat cell; a tiny
//    apply kernel finishes relu(scale*(scale>0?max:min)+shift) after finalize3.

typedef unsigned short u16;
typedef unsigned int   u32;

#define NB    16
#define NPTS  8192
#define CINF  64
#define NS    1024
#define KK    32
#define NSAMP (NB*NS*KK)   // 524288

typedef _Float16 h2v __attribute__((ext_vector_type(2)));

static __device__ __forceinline__ h2v asH2(u32 x){ union{u32 u; h2v h;} v; v.u=x; return v.h; }
static __device__ __forceinline__ u32 packh(float lo, float hi){
  union{ _Float16 h[2]; u32 u; } v;
  v.h[0]=(_Float16)lo; v.h[1]=(_Float16)hi; return v.u;
}
static __device__ __forceinline__ u32 f16bits(float z){
  union{ _Float16 h; u16 s; } v; v.h=(_Float16)z; return (u32)v.s;
}
static __device__ __forceinline__ float fdot2(h2v a, h2v b, float c){
#if __has_builtin(__builtin_amdgcn_fdot2)
  return __builtin_amdgcn_fdot2(a,b,c,false);   // v_dot2_f32_f16
#else
  return c + (float)a[0]*(float)b[0] + (float)a[1]*(float)b[1];
#endif
}

// exact-order d^2, matching numpy f32: (dx*dx + dy*dy) + dz*dz, no FMA contraction
static __device__ __forceinline__ float d2_exact(float ax,float ay,float az,float bx,float by,float bz){
  float dx=__fsub_rn(ax,bx), dy=__fsub_rn(ay,by), dz=__fsub_rn(az,bz);
  return __fadd_rn(__fadd_rn(__fmul_rn(dx,dx),__fmul_rn(dy,dy)),__fmul_rn(dz,dz));
}

// ---------------------------------------------------------------- prep ----
__global__ void prep_kernel(const float* __restrict__ W0, const float* __restrict__ W1,
                            const float* __restrict__ W2,
                            u32* __restrict__ Wp0, u32* __restrict__ Wp1, u32* __restrict__ Wp2,
                            float* __restrict__ stats)
{
  const int t = threadIdx.x;
  for (int i=t;i<768;i+=256) stats[i]=0.f;
  // W0: (64,67) -> rows of 36 uints (34 f16x2 pairs + 2 pad)
  for (int i=t;i<64*36;i+=256){
    int c = i/36, u = i - c*36;
    int j0 = 2*u, j1 = 2*u+1;
    float lo = (j0<67)? W0[c*67+j0] : 0.f;
    float hi = (j1<67)? W0[c*67+j1] : 0.f;
    Wp0[i] = packh(lo,hi);
  }
  for (int i=t;i<64*32;i+=256){            // W1 (64,64) -> 32 pairs/row
    int c = i>>5, u = i&31;
    Wp1[i] = packh(W1[c*64+2*u], W1[c*64+2*u+1]);
  }
  for (int i=t;i<128*32;i+=256){           // W2 (128,64)
    int c = i>>5, u = i&31;
    Wp2[i] = packh(W2[c*64+2*u], W2[c*64+2*u+1]);
  }
}

// ----------------------------------------------------------------- FPS ----
// one block per batch; 1024 threads, 8 points/thread in NAMED SCALARS (R5's
// array version was demoted to cache re-loads: VGPR_Count=32). Argmax carries
// (bv,bi); winner coords re-fetched via uniform broadcast load.
__global__ __launch_bounds__(1024,2) void fps_kernel(const float* __restrict__ xyz,
    float* __restrict__ out_xyz)
{
  const int b = blockIdx.x, t = threadIdx.x;
  const float* xb = xyz + (size_t)b*3*NPTS;
  __shared__ float s_v[2][16];
  __shared__ int   s_i[2][16];

#define LOADPT(i) \
  float px##i = xb[t+1024*i]; float py##i = xb[NPTS+t+1024*i]; \
  float pz##i = xb[2*NPTS+t+1024*i]; float ds##i = __builtin_inff();
  LOADPT(0) LOADPT(1) LOADPT(2) LOADPT(3) LOADPT(4) LOADPT(5) LOADPT(6) LOADPT(7)
#undef LOADPT

  float cx = xb[0], cy = xb[NPTS], cz = xb[2*NPTS];   // initial center = point 0
  const int lane = t & 63, wv = t >> 6, l16 = lane & 15;
  for (int step=0; step<NS; step++){
    if (t==0){
      out_xyz[(size_t)(b*3+0)*NS+step]=cx;
      out_xyz[(size_t)(b*3+1)*NS+step]=cy;
      out_xyz[(size_t)(b*3+2)*NS+step]=cz;
    }
    if (step==NS-1) break;

#define UPD(i) { float d2 = d2_exact(px##i,py##i,pz##i, cx,cy,cz); ds##i = fminf(ds##i, d2); }
    UPD(0) UPD(1) UPD(2) UPD(3) UPD(4) UPD(5) UPD(6) UPD(7)
#undef UPD
    float bv = ds0; int bi = t;
#define AMAX(i) if (ds##i > bv){ bv = ds##i; bi = t + 1024*i; }   // strict >: smallest idx wins
    AMAX(1) AMAX(2) AMAX(3) AMAX(4) AMAX(5) AMAX(6) AMAX(7)
#undef AMAX

    #pragma unroll
    for (int off=1; off<64; off<<=1){    // wave argmax, smallest-index tie-break
      float ov=__shfl_xor(bv,off); int oi=__shfl_xor(bi,off);
      bool take = (ov>bv) || (ov==bv && oi<bi);
      bv=take?ov:bv; bi=take?oi:bi;
    }
    const int p = step&1;                // double-buffered -> single barrier/step
    if (lane==0){ s_v[p][wv]=bv; s_i[p][wv]=bi; }
    __syncthreads();
    bv = s_v[p][l16]; bi = s_i[p][l16];  // 16 wave slots -> lanes, 4-level reduce
    #pragma unroll
    for (int off=1; off<16; off<<=1){
      float ov=__shfl_xor(bv,off); int oi=__shfl_xor(bi,off);
      bool take = (ov>bv) || (ov==bv && oi<bi);
      bv=take?ov:bv; bi=take?oi:bi;
    }
    // bi identical on all lanes/waves -> broadcast load of winner coords
    cx = xb[bi]; cy = xb[NPTS+bi]; cz = xb[2*NPTS+bi];
  }
}

// ---------------------------------------------------------- ball query ----
// one wave per center; first 32 ascending indices with d2 < 0.04; pad with first.
__global__ __launch_bounds__(256) void ballq_kernel(const float* __restrict__ xyz,
    const float* __restrict__ out_xyz, u16* __restrict__ gidx)
{
  const int gid = blockIdx.x*4 + (threadIdx.x>>6);
  const int lane = threadIdx.x & 63;
  const int b = gid >> 10, s = gid & (NS-1);
  const float* xb = xyz + (size_t)b*3*NPTS;
  const float cx = out_xyz[(size_t)(b*3+0)*NS+s];
  const float cy = out_xyz[(size_t)(b*3+1)*NS+s];
  const float cz = out_xyz[(size_t)(b*3+2)*NS+s];
  u16* out = gidx + (size_t)gid*KK;
  int cnt=0, first=-1;
  for (int base=0; base<NPTS; base+=64){
    const int pidx = base + lane;
    float d2 = d2_exact(cx,cy,cz, xb[pidx], xb[NPTS+pidx], xb[2*NPTS+pidx]);
    bool within = d2 < 0.04f;
    unsigned long long m = __ballot(within);
    if (m){
      if (first<0) first = base + (__ffsll(m)-1);
      int pos = cnt + (int)__popcll(m & ((1ull<<lane)-1ull));
      if (within && pos<KK) out[pos]=(u16)pidx;
      cnt += (int)__popcll(m);
      if (cnt>=KK) break;
    }
  }
  if (first<0) first=0;                  // unreachable (center self-hit)
  for (int posi = cnt + lane; posi < KK; posi += 64) out[posi]=(u16)first;
}

// --------------------------------------------------------------- MLP -----
// wrow is wave-uniform -> s_load; dot2 with SGPR weight operand. 2 acc chains.
template<int PAIRS>
static __device__ __forceinline__ float dotrow(const u32* __restrict__ wrow, const u32* x){
  float a=0.f, b=0.f;
  #pragma unroll
  for (int u=0;u<PAIRS;u+=2){
    a = fdot2(asH2(x[u]),   asH2(wrow[u]),   a);
    if (u+1<PAIRS) b = fdot2(asH2(x[u+1]), asH2(wrow[u+1]), b);
  }
  return __fadd_rn(a,b);
}

// STAGE 0: stats of y1 | 1: stats of y2 | 2: stats of y3 + packed (max,min) over K
template<int STAGE>
__global__ __launch_bounds__(256,4) void mlp_pass(
    const float* __restrict__ xyz, const float* __restrict__ feat,
    const float* __restrict__ out_xyz, const u16* __restrict__ gidx,
    const u32* __restrict__ Wp0, const u32* __restrict__ Wp1, const u32* __restrict__ Wp2,
    const float* __restrict__ affine, float* __restrict__ stats, u32* __restrict__ outMM)
{
  constexpr int TCO = (STAGE==2)?128:64;       // stats channel count
  constexpr int RB  = (TCO==128)?16:32;        // LDS stat bins stripe
  __shared__ u32   hbuf[(STAGE>=1)? 256*34 : 4];   // per-thread h staging (stride 34 dwords)
  __shared__ float bins[TCO*2*RB];

  const int t = threadIdx.x;
  for (int i=t;i<TCO*2*RB;i+=256) bins[i]=0.f;
  __syncthreads();

  const int ss = blockIdx.x*256 + t;           // flat (b,s,k)
  const int b = ss >> 15;
  const int s = (ss >> 5) & (NS-1);
  const int g = ((int)gidx[ss]) & (NPTS-1);    // clamp: never OOB
  const float* xb = xyz + (size_t)b*3*NPTS;
  const float* fb = feat + (size_t)b*CINF*NPTS;
  const float cx = out_xyz[(size_t)(b*3+0)*NS+s];
  const float cy = out_xyz[(size_t)(b*3+1)*NS+s];
  const float cz = out_xyz[(size_t)(b*3+2)*NS+s];

  // gather x = [xyz[g]-center ; feat[:,g]] as 34 packed f16 pairs (j=67 padded 0)
  u32 xh[34];
  {
    float dx = __fsub_rn(xb[g],        cx);
    float dy = __fsub_rn(xb[NPTS+g],   cy);
    float dz = __fsub_rn(xb[2*NPTS+g], cz);
    xh[0] = packh(dx,dy);
    xh[1] = packh(dz, fb[g]);                          // f[0]
    #pragma unroll
    for (int u=2;u<33;u++)                             // f[2u-3], f[2u-2]
      xh[u] = packh(fb[(size_t)(2*u-3)*NPTS+g], fb[(size_t)(2*u-2)*NPTS+g]);
    xh[33] = packh(fb[(size_t)63*NPTS+g], 0.f);        // f[63], pad
  }

  const int r = t & (RB-1);
  u32 pend=0;

  // ---- layer 1 (67->64) ----
  #pragma unroll 2
  for (int c=0;c<64;c++){
    float y = dotrow<34>(Wp0 + c*36, xh);
    if constexpr (STAGE==0){
      atomicAdd(&bins[c*RB+r], y);
      atomicAdd(&bins[TCO*RB + c*RB+r], __fmul_rn(y,y));
    } else {
      float z = fmaxf(fmaf(y, affine[2*c], affine[2*c+1]), 0.f);
      u32 hb = f16bits(z);
      if ((c&1)==0) pend = hb; else hbuf[t*34 + (c>>1)] = pend | (hb<<16);
    }
  }

  if constexpr (STAGE>=1){
    alignas(16) u32 ha[32];
    #pragma unroll
    for (int u=0;u<16;u++) *(uint2*)&ha[2*u] = *(const uint2*)&hbuf[t*34 + 2*u];
    // ---- layer 2 (64->64) ----
    #pragma unroll 2
    for (int c=0;c<64;c++){
      float y = dotrow<32>(Wp1 + c*32, ha);
      if constexpr (STAGE==1){
        atomicAdd(&bins[c*RB+r], y);
        atomicAdd(&bins[TCO*RB + c*RB+r], __fmul_rn(y,y));
      } else {
        float z = fmaxf(fmaf(y, affine[256+2*c], affine[256+2*c+1]), 0.f);
        u32 hb = f16bits(z);
        if ((c&1)==0) pend = hb; else hbuf[t*34 + (c>>1)] = pend | (hb<<16);
      }
    }
    if constexpr (STAGE==2){
      #pragma unroll
      for (int u=0;u<16;u++) *(uint2*)&ha[2*u] = *(const uint2*)&hbuf[t*34 + 2*u];
      // ---- layer 3 (64->128): stats + K-group max/min (packed f16 -> out cell)
      #pragma unroll 2
      for (int c=0;c<128;c++){
        float y = dotrow<32>(Wp2 + c*32, ha);
        atomicAdd(&bins[c*RB+r], y);
        atomicAdd(&bins[TCO*RB + c*RB+r], __fmul_rn(y,y));
        float mx = y, mn = y;
        #pragma unroll
        for (int off=1; off<32; off<<=1){               // K=32 = half-wave
          mx = fmaxf(mx, __shfl_xor(mx, off));
          mn = fminf(mn, __shfl_xor(mn, off));
        }
        if ((t&31)==0) outMM[((size_t)b*128 + c)*NS + s] = packh(mx, mn);
      }
    }
  }

  __syncthreads();
  if (t < TCO){
    float s1=0.f, s2=0.f;
    #pragma unroll
    for (int q=0;q<RB;q++){ s1 += bins[t*RB+q]; s2 += bins[TCO*RB+t*RB+q]; }
    atomicAdd(&stats[STAGE*256 + 2*t],   s1);
    atomicAdd(&stats[STAGE*256 + 2*t+1], s2);
  }
}

// ----------------------------------------------------------- finalize ----
__global__ void finalize_kernel(const float* __restrict__ st, float* __restrict__ af,
                                const float* __restrict__ gamma, const float* __restrict__ beta, int C)
{
  int c = threadIdx.x;
  if (c < C){
    float mean = st[2*c] * (1.f/524288.f);
    float var  = fmaxf(st[2*c+1] * (1.f/524288.f) - mean*mean, 0.f);
    float rstd = 1.f / sqrtf(var + 1e-5f);
    float sc = rstd * gamma[c];
    af[2*c]   = sc;
    af[2*c+1] = beta[c] - mean*sc;
  }
}

// -------------------------------------------------------------- apply ----
// out_feat[i] currently holds packed f16 (max_k y3, min_k y3); finish BN+relu.
// scale>0 -> max wins after affine; scale<0 -> min; scale==0 -> relu(shift) either way.
__global__ void apply_kernel(const float* __restrict__ affine, float* __restrict__ outF)
{
  const int i = blockIdx.x*256 + threadIdx.x;      // 16*128*1024 elements
  const int c = (i >> 10) & 127;
  u32 v = ((const u32*)outF)[i];
  h2v h = asH2(v);
  float sc = affine[512+2*c], sh = affine[512+2*c+1];
  float cand = (sc > 0.f) ? (float)h[0] : (float)h[1];
  outF[i] = fmaxf(fmaf(cand, sc, sh), 0.f);
}

// ------------------------------------------------------------- launch ----
extern "C" void kernel_launch(void* const* d_in, const int* in_sizes, int n_in,
                              void* d_out, int out_size, void* d_ws, size_t ws_size,
                              hipStream_t stream)
{
  (void)in_sizes; (void)n_in; (void)out_size; (void)ws_size;
  const float* xyz  = (const float*)d_in[0];
  const float* feat = (const float*)d_in[1];
  const float* W0 = (const float*)d_in[2];
  const float* g0 = (const float*)d_in[3];
  const float* b0 = (const float*)d_in[4];
  const float* W1 = (const float*)d_in[5];
  const float* g1 = (const float*)d_in[6];
  const float* b1 = (const float*)d_in[7];
  const float* W2 = (const float*)d_in[8];
  const float* g2 = (const float*)d_in[9];
  const float* b2 = (const float*)d_in[10];

  char* ws = (char*)d_ws;                      // 1,088,512 B total (proven safe)
  u16*   gidx    = (u16*)  (ws + 0);           // 524288 u16  = 1048576 B
  u32*   Wp0     = (u32*)  (ws + 1048576);     // 64*36 u32   =    9216 B
  u32*   Wp1     = (u32*)  (ws + 1057792);     // 64*32 u32   =    8192 B
  u32*   Wp2     = (u32*)  (ws + 1065984);     // 128*32 u32  =   16384 B
  float* stats   = (float*)(ws + 1082368);     // 3*128*2 f32 =    3072 B
  float* affine  = (float*)(ws + 1085440);     // 3*128*2 f32 =    3072 B

  float* out_xyz  = (float*)d_out;                         // (16,3,1024) f32
  float* out_feat = (float*)d_out + (size_t)NB*3*NS;       // (16,128,1024) f32

  prep_kernel<<<1,256,0,stream>>>(W0,W1,W2,Wp0,Wp1,Wp2,stats);
  fps_kernel<<<NB,1024,0,stream>>>(xyz, out_xyz);
  ballq_kernel<<<NB*NS/4,256,0,stream>>>(xyz, out_xyz, gidx);

  mlp_pass<0><<<NSAMP/256,256,0,stream>>>(xyz,feat,out_xyz,gidx,Wp0,Wp1,Wp2,affine,stats,(u32*)out_feat);
  finalize_kernel<<<1,128,0,stream>>>(stats,     affine,     g0,b0, 64);
  mlp_pass<1><<<NSAMP/256,256,0,stream>>>(xyz,feat,out_xyz,gidx,Wp0,Wp1,Wp2,affine,stats,(u32*)out_feat);
  finalize_kernel<<<1,128,0,stream>>>(stats+256, affine+256, g1,b1, 64);
  mlp_pass<2><<<NSAMP/256,256,0,stream>>>(xyz,feat,out_xyz,gidx,Wp0,Wp1,Wp2,affine,stats,(u32*)out_feat);
  finalize_kernel<<<1,128,0,stream>>>(stats+512, affine+512, g2,b2, 128);
  apply_kernel<<<(NB*128*NS)/256,256,0,stream>>>(affine, out_feat);
}